// Round 2
// baseline (1272.932 us; speedup 1.0000x reference)
//
#include <hip/hip_runtime.h>

// ConvLSTM on MI355X — round 2.
//  - xpose_kernel: (B,T,C,S) f32 -> xT[b][s][t*C+c] bf16 (64 MiB in d_ws).
//  - gatex_kernel: precompute x-part of conv + bias for ALL (b,s) on all 256 CUs:
//      gateX[b][s][gc/4][t][4] bf16 (512 MiB in d_ws). Removes 1/3 of the
//      recurrent MFMA work and all x staging from the sequential kernel.
//  - convlstm_gx_kernel: 32 blocks (1/batch), 512 thr. Per step: acc init from
//      prefetched gateX, h-part conv via MFMA (K=192), gates software-pipelined
//      into the MFMA shadow (gates of chunk c-1 issued under MFMAs of chunk c),
//      ONE barrier/step (red double-buffered), h-only LDS Z buffer.
//  - convlstm_kernel: round-1 proven kernel, used if ws_size is too small.

#define Bb 32
#define Tt 128
#define Cc 32
#define Ss 256
#define Hh 64

typedef __bf16 bf16x8 __attribute__((ext_vector_type(8)));
typedef short  short8 __attribute__((ext_vector_type(8)));
typedef float  f32x4  __attribute__((ext_vector_type(4)));
typedef unsigned short u16;
typedef unsigned int   u32;

__device__ __forceinline__ u16 f2bf(float f) {
    u32 u = __float_as_uint(f);
    u = (u + 0x7FFFu + ((u >> 16) & 1u)) >> 16;  // RNE
    return (u16)u;
}
__device__ __forceinline__ float bfl(u32 d) { return __uint_as_float(d << 16); }
__device__ __forceinline__ float bfh(u32 d) { return __uint_as_float(d & 0xffff0000u); }
__device__ __forceinline__ float fsig(float x) {
    float e = __expf(-x);
    return __builtin_amdgcn_rcpf(1.0f + e);
}
__device__ __forceinline__ float ftanh_(float x) {
    float e = __expf(2.0f * x);
    return 1.0f - 2.0f * __builtin_amdgcn_rcpf(e + 1.0f);
}

// ---------------- transpose: x (B,T,C,S) f32 -> xT (B,S,T*C) bf16 ----------------
__global__ __launch_bounds__(256) void xpose_kernel(const float* __restrict__ x,
                                                    u16* __restrict__ xT) {
    __shared__ u16 tile[64][130];
    const int tc0 = blockIdx.x * 128;
    const int s0  = blockIdx.y * 64;
    const int b   = blockIdx.z;
    const int tid = threadIdx.x;
    const float* xb = x + (size_t)b * (Tt * Cc * Ss);
#pragma unroll
    for (int i = 0; i < 32; ++i) {
        const int tcr = (tid >> 6) + 4 * i;
        const int sr  = tid & 63;
        tile[sr][tcr] = f2bf(xb[(size_t)(tc0 + tcr) * Ss + s0 + sr]);
    }
    __syncthreads();
    u32* xTo = (u32*)(xT + (size_t)b * (Ss * Tt * Cc));
#pragma unroll
    for (int j = 0; j < 16; ++j) {
        const int sw = (tid >> 6) + 4 * j;
        const int tw = (tid & 63) * 2;
        xTo[(((size_t)(s0 + sw)) * (Tt * Cc) + tc0 + tw) >> 1] = *(const u32*)&tile[sw][tw];
    }
}

// ---------------- gateX precompute: x-part of conv + bias, all (b,s) ----------------
// gateX layout: [b][s][gcq=gc/4][t][r] bf16, gcq in 0..63, t in 0..127, r in 0..3.
__global__ __launch_bounds__(256) void gatex_kernel(
    const float* __restrict__ Wc, const float* __restrict__ bc,
    const u16* __restrict__ xT, u16* __restrict__ gateX) {

    __shared__ u16 zx[130][40];  // t rows -1..128 (halo zero), 32 x-channels + pad
    const int s   = blockIdx.x;
    const int b   = blockIdx.y;
    const int tid = threadIdx.x;
    const int g   = tid >> 6;    // wave = gate
    const int lane = tid & 63;
    const int l15 = lane & 15;
    const int q   = lane >> 4;

    if (tid < 40) {  // zero halo rows 0 and 129 (20 dwords each)
        u32* zp = (u32*)&zx[(tid < 20) ? 0 : 129][0];
        zp[(tid < 20) ? tid : tid - 20] = 0;
    }
    const u16* xp = xT + ((size_t)b * Ss + s) * (Tt * Cc);
#pragma unroll
    for (int i = 0; i < 4; ++i) {
        const int idx = tid + 256 * i;   // uint2 index 0..1023
        const int e = idx * 4;
        *(uint2*)&zx[1 + (e >> 5)][e & 31] = *(const uint2*)(xp + e);
    }

    // A fragments: x-part weights only (cin = 8q+j), afr[mt][k]
    bf16x8 afr[4][3];
#pragma unroll
    for (int mt = 0; mt < 4; ++mt)
#pragma unroll
        for (int k = 0; k < 3; ++k) {
            const int gc = 64 * g + 16 * mt + l15;
            short8 t;
#pragma unroll
            for (int j = 0; j < 8; ++j) t[j] = (short)f2bf(Wc[gc * 288 + (8 * q + j) * 3 + k]);
            afr[mt][k] = __builtin_bit_cast(bf16x8, t);
        }
    f32x4 bcv[4];
#pragma unroll
    for (int mt = 0; mt < 4; ++mt) bcv[mt] = *(const f32x4*)&bc[64 * g + 16 * mt + 4 * q];

    __syncthreads();

    u16* gxo = gateX + ((size_t)b * Ss + s) * (64 * 128 * 4);
#pragma unroll
    for (int nt = 0; nt < 8; ++nt) {
        f32x4 acc[4];
#pragma unroll
        for (int mt = 0; mt < 4; ++mt) acc[mt] = bcv[mt];
#pragma unroll
        for (int k = 0; k < 3; ++k) {
            bf16x8 bfr = *(const bf16x8*)&zx[16 * nt + l15 + k][8 * q];
            acc[0] = __builtin_amdgcn_mfma_f32_16x16x32_bf16(afr[0][k], bfr, acc[0], 0, 0, 0);
            acc[1] = __builtin_amdgcn_mfma_f32_16x16x32_bf16(afr[1][k], bfr, acc[1], 0, 0, 0);
            acc[2] = __builtin_amdgcn_mfma_f32_16x16x32_bf16(afr[2][k], bfr, acc[2], 0, 0, 0);
            acc[3] = __builtin_amdgcn_mfma_f32_16x16x32_bf16(afr[3][k], bfr, acc[3], 0, 0, 0);
        }
#pragma unroll
        for (int mt = 0; mt < 4; ++mt) {
            uint2 hw;
            hw.x = (u32)f2bf(acc[mt][0]) | ((u32)f2bf(acc[mt][1]) << 16);
            hw.y = (u32)f2bf(acc[mt][2]) | ((u32)f2bf(acc[mt][3]) << 16);
            const int gcq = 16 * g + 4 * mt + q;
            *(uint2*)(gxo + ((size_t)gcq * 128 + 16 * nt + l15) * 4) = hw;
        }
    }
}

// ---------------- recurrent kernel (gateX path): one block per batch ----------------
__global__ __launch_bounds__(512, 2) void convlstm_gx_kernel(
    const float* __restrict__ Wc, const float* __restrict__ Wl,
    const float* __restrict__ bl, const u16* __restrict__ gateX,
    float* __restrict__ out) {

    __shared__ u16  zbuf[2][130][72];   // h-only Z: rows t -1..128, 64 h-ch + pad
    __shared__ float red[2][8][16];

    const int b    = blockIdx.x;
    const int tid  = threadIdx.x;
    const int w    = tid >> 6;
    const int lane = tid & 63;
    const int l15  = lane & 15;
    const int q    = lane >> 4;
    const int ht   = w >> 1;
    const int th   = w & 1;

    {   // zero both Z buffers (h(-1)=0, halos stay 0)
        u32* z32 = (u32*)&zbuf[0][0][0];
        for (int i = tid; i < (2 * 130 * 72) / 2; i += 512) z32[i] = 0;
    }

    // h-part weight fragments: afr[gate][tap][ks], cin = 32 + 32*ks + 8q + j
    bf16x8 afr[4][3][2];
#pragma unroll
    for (int g = 0; g < 4; ++g)
#pragma unroll
        for (int k = 0; k < 3; ++k)
#pragma unroll
            for (int ks = 0; ks < 2; ++ks) {
                const int gc = 64 * g + 16 * ht + l15;
                short8 t;
#pragma unroll
                for (int j = 0; j < 8; ++j)
                    t[j] = (short)f2bf(Wc[gc * 288 + (32 + 32 * ks + 8 * q + j) * 3 + k]);
                afr[g][k][ks] = __builtin_bit_cast(bf16x8, t);
            }

    float wlv[4];
#pragma unroll
    for (int nj = 0; nj < 4; ++nj) wlv[nj] = Wl[64 * th + 16 * nj + l15];
    const float bl0 = bl[0];

    float cst[16];
#pragma unroll
    for (int i = 0; i < 16; ++i) cst[i] = 0.0f;

    // gateX per-lane offsets (u16 units): [nj][g]
    const u16* gxb = gateX + (size_t)b * Ss * (64 * 128 * 4);
    int off[16];
#pragma unroll
    for (int nj = 0; nj < 4; ++nj)
#pragma unroll
        for (int g = 0; g < 4; ++g)
            off[nj * 4 + g] = (((16 * g + 4 * ht + q) * 128) + 64 * th + 16 * nj + l15) * 4;

    uint2 gx[16];
#pragma unroll
    for (int i = 0; i < 16; ++i) gx[i] = *(const uint2*)(gxb + off[i]);  // s=0

    __syncthreads();

    float* outb = out + (size_t)b * (Ss * Hh);

    for (int s = 0; s < Ss; ++s) {
        if (tid < 64 && s > 0) {  // emit output for step s-1
            const int ps = (s - 1) & 1;
            float v = red[ps][(tid >> 4) * 2][tid & 15] + red[ps][(tid >> 4) * 2 + 1][tid & 15] + bl0;
            outb[(size_t)(s - 1) * Hh + tid] = fsig(v);
        }

        const u16 (*zb)[72] = zbuf[(s & 1) ^ 1];  // h(s-1)
        u16 (*zn)[72] = zbuf[s & 1];              // h(s)

        float partial[4] = {0.f, 0.f, 0.f, 0.f};
        f32x4 acc[2][4];

#pragma unroll
        for (int c = 0; c < 5; ++c) {
            if (c < 4) {
                // init acc(c) from gateX (x-part + bias, prefetched last step)
                {
                    const uint2 v0 = gx[c * 4 + 0], v1 = gx[c * 4 + 1];
                    const uint2 v2 = gx[c * 4 + 2], v3 = gx[c * 4 + 3];
                    acc[c & 1][0] = (f32x4){bfl(v0.x), bfh(v0.x), bfl(v0.y), bfh(v0.y)};
                    acc[c & 1][1] = (f32x4){bfl(v1.x), bfh(v1.x), bfl(v1.y), bfh(v1.y)};
                    acc[c & 1][2] = (f32x4){bfl(v2.x), bfh(v2.x), bfl(v2.y), bfh(v2.y)};
                    acc[c & 1][3] = (f32x4){bfl(v3.x), bfh(v3.x), bfl(v3.y), bfh(v3.y)};
                }
                if (c == 3 && s + 1 < Ss) {  // prefetch gateX(s+1)
                    const u16* gs = gxb + (size_t)(s + 1) * (64 * 128 * 4);
#pragma unroll
                    for (int i = 0; i < 16; ++i) gx[i] = *(const uint2*)(gs + off[i]);
                }
                // h-part MFMAs for chunk c (nj = c): K = 64 h-ch x 3 taps
                {
                    const int tb = 64 * th + 16 * c + l15;
#pragma unroll
                    for (int k = 0; k < 3; ++k)
#pragma unroll
                        for (int ks = 0; ks < 2; ++ks) {
                            bf16x8 bfr = *(const bf16x8*)&zb[tb + k][32 * ks + 8 * q];
                            acc[c & 1][0] = __builtin_amdgcn_mfma_f32_16x16x32_bf16(afr[0][k][ks], bfr, acc[c & 1][0], 0, 0, 0);
                            acc[c & 1][1] = __builtin_amdgcn_mfma_f32_16x16x32_bf16(afr[1][k][ks], bfr, acc[c & 1][1], 0, 0, 0);
                            acc[c & 1][2] = __builtin_amdgcn_mfma_f32_16x16x32_bf16(afr[2][k][ks], bfr, acc[c & 1][2], 0, 0, 0);
                            acc[c & 1][3] = __builtin_amdgcn_mfma_f32_16x16x32_bf16(afr[3][k][ks], bfr, acc[c & 1][3], 0, 0, 0);
                        }
                }
            }
            if (c > 0) {  // gates for chunk c-1, in the MFMA shadow of chunk c
                const int nj = c - 1;
                u16 hp[4];
#pragma unroll
                for (int r = 0; r < 4; ++r) {
                    const float ci  = acc[nj & 1][0][r];
                    const float cf  = acc[nj & 1][1][r];
                    const float cop = acc[nj & 1][2][r];
                    const float cg  = acc[nj & 1][3][r];
                    const float ig = fsig(ci);
                    const float fg = fsig(cf);
                    const float og = fsig(cop);
                    const float gg = ftanh_(cg);
                    const float cv = fg * cst[nj * 4 + r] + ig * gg;
                    cst[nj * 4 + r] = cv;
                    const float hv = og * ftanh_(cv);
                    partial[r] += hv * wlv[nj];
                    hp[r] = f2bf(hv);
                }
                uint2 hw;
                hw.x = (u32)hp[0] | ((u32)hp[1] << 16);
                hw.y = (u32)hp[2] | ((u32)hp[3] << 16);
                *(uint2*)&zn[1 + 64 * th + 16 * nj + l15][16 * ht + 4 * q] = hw;
            }
        }

#pragma unroll
        for (int r = 0; r < 4; ++r) {
#pragma unroll
            for (int offl = 1; offl <= 8; offl <<= 1)
                partial[r] += __shfl_xor(partial[r], offl, 64);
        }
        if (l15 == 0) {
#pragma unroll
            for (int r = 0; r < 4; ++r) red[s & 1][w][4 * q + r] = partial[r];
        }
        __syncthreads();  // h(s) + red visible
    }

    if (tid < 64) {  // final output, s = Ss-1
        const int ps = (Ss - 1) & 1;
        float v = red[ps][(tid >> 4) * 2][tid & 15] + red[ps][(tid >> 4) * 2 + 1][tid & 15] + bl0;
        outb[(size_t)(Ss - 1) * Hh + tid] = fsig(v);
    }
}

// ---------------- round-1 fallback kernel (used if ws_size too small) ----------------
__global__ __launch_bounds__(512, 2) void convlstm_kernel(
    const float* __restrict__ Wc, const float* __restrict__ bc,
    const float* __restrict__ Wl, const float* __restrict__ bl,
    const u16* __restrict__ xT, float* __restrict__ out) {

    __shared__ u16  zbuf[2][130][104];
    __shared__ float red[8][16];
    __shared__ float bcl[256];

    const int b    = blockIdx.x;
    const int tid  = threadIdx.x;
    const int w    = tid >> 6;
    const int lane = tid & 63;
    const int l15  = lane & 15;
    const int q    = lane >> 4;
    const int ht   = w >> 1;
    const int th   = w & 1;

    {
        u32* z32 = (u32*)&zbuf[0][0][0];
        for (int i = tid; i < (2 * 130 * 104) / 2; i += 512) z32[i] = 0;
    }
    if (tid < 256) bcl[tid] = bc[tid];

    bf16x8 afr[4][3][3];
#pragma unroll
    for (int g = 0; g < 4; ++g) {
#pragma unroll
        for (int k = 0; k < 3; ++k) {
#pragma unroll
            for (int ks = 0; ks < 3; ++ks) {
                const int gc = 64 * g + 16 * ht + l15;
                short8 t;
#pragma unroll
                for (int j = 0; j < 8; ++j) {
                    const int c = 32 * ks + 8 * q + j;
                    t[j] = (short)f2bf(Wc[gc * 288 + c * 3 + k]);
                }
                afr[g][k][ks] = __builtin_bit_cast(bf16x8, t);
            }
        }
    }

    float wlv[4];
#pragma unroll
    for (int nj = 0; nj < 4; ++nj) wlv[nj] = Wl[64 * th + 16 * nj + l15];
    const float bl0 = bl[0];

    float cst[16];
#pragma unroll
    for (int i = 0; i < 16; ++i) cst[i] = 0.0f;

    const int xt = tid >> 2;
    const int xc = (tid & 3) * 8;
    const u16* xTb = xT + (size_t)b * (Ss * Tt * Cc);

    {
        uint4 xv0 = *(const uint4*)(xTb + 0 + xt * 32 + xc);
        __syncthreads();
        *(uint4*)&zbuf[0][1 + xt][xc] = xv0;
        __syncthreads();
    }

    float* outb = out + (size_t)b * (Ss * Hh);
    int p = 0;

    for (int s = 0; s < Ss; ++s) {
        uint4 xv;
        const bool havex = (s + 1) < Ss;
        if (havex) xv = *(const uint4*)(xTb + (size_t)(s + 1) * (Tt * Cc) + xt * 32 + xc);

        if (tid < 64 && s > 0) {
            float v = red[(tid >> 4) * 2][tid & 15] + red[(tid >> 4) * 2 + 1][tid & 15] + bl0;
            outb[(size_t)(s - 1) * Hh + tid] = fsig(v);
        }
        __syncthreads();

        const u16 (*zb)[104] = zbuf[p];
        u16 (*zn)[104] = zbuf[p ^ 1];

        float partial[4] = {0.f, 0.f, 0.f, 0.f};

#pragma unroll
        for (int half = 0; half < 2; ++half) {
            f32x4 acc[4][2];
#pragma unroll
            for (int g = 0; g < 4; ++g)
#pragma unroll
                for (int njl = 0; njl < 2; ++njl)
                    acc[g][njl] = (f32x4){0.f, 0.f, 0.f, 0.f};

#pragma unroll
            for (int njl = 0; njl < 2; ++njl) {
                const int nj = half * 2 + njl;
                const int tb = 64 * th + 16 * nj + l15;
#pragma unroll
                for (int k = 0; k < 3; ++k) {
#pragma unroll
                    for (int ks = 0; ks < 3; ++ks) {
                        bf16x8 bfr = *(const bf16x8*)&zb[tb + k][32 * ks + 8 * q];
                        acc[0][njl] = __builtin_amdgcn_mfma_f32_16x16x32_bf16(afr[0][k][ks], bfr, acc[0][njl], 0, 0, 0);
                        acc[1][njl] = __builtin_amdgcn_mfma_f32_16x16x32_bf16(afr[1][k][ks], bfr, acc[1][njl], 0, 0, 0);
                        acc[2][njl] = __builtin_amdgcn_mfma_f32_16x16x32_bf16(afr[2][k][ks], bfr, acc[2][njl], 0, 0, 0);
                        acc[3][njl] = __builtin_amdgcn_mfma_f32_16x16x32_bf16(afr[3][k][ks], bfr, acc[3][njl], 0, 0, 0);
                    }
                }
            }

#pragma unroll
            for (int njl = 0; njl < 2; ++njl) {
                const int nj = half * 2 + njl;
                u16 hp[4];
#pragma unroll
                for (int r = 0; r < 4; ++r) {
                    const int hl = 4 * q + r;
                    const float ci  = acc[0][njl][r] + bcl[0   + 16 * ht + hl];
                    const float cf  = acc[1][njl][r] + bcl[64  + 16 * ht + hl];
                    const float cop = acc[2][njl][r] + bcl[128 + 16 * ht + hl];
                    const float cg  = acc[3][njl][r] + bcl[192 + 16 * ht + hl];
                    const float ig = fsig(ci);
                    const float fg = fsig(cf);
                    const float og = fsig(cop);
                    const float gg = ftanh_(cg);
                    const float cv = fg * cst[nj * 4 + r] + ig * gg;
                    cst[nj * 4 + r] = cv;
                    const float hv = og * ftanh_(cv);
                    partial[r] += hv * wlv[nj];
                    hp[r] = f2bf(hv);
                }
                uint2 hw;
                hw.x = (u32)hp[0] | ((u32)hp[1] << 16);
                hw.y = (u32)hp[2] | ((u32)hp[3] << 16);
                *(uint2*)&zn[1 + 64 * th + 16 * nj + l15][32 + 16 * ht + 4 * q] = hw;
            }
        }

        if (havex) *(uint4*)&zn[1 + xt][xc] = xv;

#pragma unroll
        for (int r = 0; r < 4; ++r) {
#pragma unroll
            for (int offl = 1; offl <= 8; offl <<= 1)
                partial[r] += __shfl_xor(partial[r], offl, 64);
        }
        if (l15 == 0) {
#pragma unroll
            for (int r = 0; r < 4; ++r) red[w][4 * q + r] = partial[r];
        }
        __syncthreads();
        p ^= 1;
    }

    if (tid < 64) {
        float v = red[(tid >> 4) * 2][tid & 15] + red[(tid >> 4) * 2 + 1][tid & 15] + bl0;
        outb[(size_t)(Ss - 1) * Hh + tid] = fsig(v);
    }
}

extern "C" void kernel_launch(void* const* d_in, const int* in_sizes, int n_in,
                              void* d_out, int out_size, void* d_ws, size_t ws_size,
                              hipStream_t stream) {
    const float* x  = (const float*)d_in[0];
    const float* Wc = (const float*)d_in[1];
    const float* bc = (const float*)d_in[2];
    const float* Wl = (const float*)d_in[3];
    const float* bl = (const float*)d_in[4];
    float* out = (float*)d_out;

    u16* xT = (u16*)d_ws;
    const size_t XT_BYTES = (size_t)Bb * Ss * Tt * Cc * 2;            // 64 MiB
    const size_t GX_BYTES = (size_t)Bb * Ss * 4 * Hh * Tt * 2;        // 512 MiB

    dim3 tgrid(Tt * Cc / 128, Ss / 64, Bb);
    xpose_kernel<<<tgrid, 256, 0, stream>>>(x, xT);

    if (ws_size >= XT_BYTES + GX_BYTES) {
        u16* gateX = (u16*)((char*)d_ws + XT_BYTES);
        gatex_kernel<<<dim3(Ss, Bb), 256, 0, stream>>>(Wc, bc, xT, gateX);
        convlstm_gx_kernel<<<Bb, 512, 0, stream>>>(Wc, Wl, bl, gateX, out);
    } else {
        convlstm_kernel<<<Bb, 512, 0, stream>>>(Wc, bc, Wl, bl, xT, out);
    }
}